// Round 5
// baseline (287.336 us; speedup 1.0000x reference)
//
#include <hip/hip_runtime.h>
#include <hip/hip_cooperative_groups.h>
#include <math.h>

namespace cg = cooperative_groups;

static constexpr int NPOS  = 32 * 56 * 56;   // 100352 spatial positions
static constexpr int CCH   = 256;            // channels
static constexpr int FGRID = 1024;           // fused grid (4 blocks/CU, 16 waves/CU)
static constexpr double EPSV = 1e-6;

// ws layout (bytes):
//   S      [896] f64      @ 0        (7168 B)
//   Mmat   [64*16] f32    @ 7168     (4096 B)   (fallback path only)
//   offv   [256] f32      @ 11264    (1024 B)   (fallback path only)
//   partial[grid][14][64] @ 12288    (fused: 1024*896*4 = 3670016 B)

// ---------------------------------------------------------------------------
// f32 Jacobi solve of one 4x4: S[896] f64 sums -> M (row-major 16) + off[4].
// Inlined into both fused and fallback paths. d = which of the 64 groups.
// ---------------------------------------------------------------------------
__device__ __forceinline__ void solve_one(const double* __restrict__ S,
                                          const float* __restrict__ beta,
                                          const float* __restrict__ grr, const float* __restrict__ gri,
                                          const float* __restrict__ grj, const float* __restrict__ grk,
                                          const float* __restrict__ gii, const float* __restrict__ gij,
                                          const float* __restrict__ gik, const float* __restrict__ gjj,
                                          const float* __restrict__ gjk, const float* __restrict__ gkk,
                                          int d, float* Mout /*16*/, float* offout /*4*/) {
  const double invM = 1.0 / (double)NPOS;
  double mu[4];
  mu[0] = S[0*64+d]*invM; mu[1] = S[1*64+d]*invM;
  mu[2] = S[2*64+d]*invM; mu[3] = S[3*64+d]*invM;

  float A[4][4];
  A[0][0] = (float)(S[4*64+d]*invM  - mu[0]*mu[0] + EPSV);
  A[0][1] = A[1][0] = (float)(S[5*64+d]*invM  - mu[0]*mu[1]);
  A[0][2] = A[2][0] = (float)(S[6*64+d]*invM  - mu[0]*mu[2]);
  A[0][3] = A[3][0] = (float)(S[7*64+d]*invM  - mu[0]*mu[3]);
  A[1][1] = (float)(S[8*64+d]*invM  - mu[1]*mu[1] + EPSV);
  A[1][2] = A[2][1] = (float)(S[9*64+d]*invM  - mu[1]*mu[2]);
  A[1][3] = A[3][1] = (float)(S[10*64+d]*invM - mu[1]*mu[3]);
  A[2][2] = (float)(S[11*64+d]*invM - mu[2]*mu[2] + EPSV);
  A[2][3] = A[3][2] = (float)(S[12*64+d]*invM - mu[2]*mu[3]);
  A[3][3] = (float)(S[13*64+d]*invM - mu[3]*mu[3] + EPSV);

  float U[4][4] = {{1,0,0,0},{0,1,0,0},{0,0,1,0},{0,0,0,1}};

#pragma unroll 1
  for (int sweep = 0; sweep < 6; ++sweep) {
#pragma unroll
    for (int p = 0; p < 3; ++p) {
#pragma unroll
      for (int q = p + 1; q < 4; ++q) {
        float apq = A[p][q];
        if (fabsf(apq) > 1e-30f) {
          float theta = (A[q][q] - A[p][p]) / (2.0f * apq);
          float t = 1.0f / (fabsf(theta) + sqrtf(fmaf(theta, theta, 1.0f)));
          if (theta < 0.0f) t = -t;
          float c = rsqrtf(fmaf(t, t, 1.0f));
          float s = t * c;
#pragma unroll
          for (int r = 0; r < 4; ++r) {
            float arp = A[r][p], arq = A[r][q];
            A[r][p] = c*arp - s*arq;  A[r][q] = s*arp + c*arq;
          }
#pragma unroll
          for (int r = 0; r < 4; ++r) {
            float apr = A[p][r], aqr = A[q][r];
            A[p][r] = c*apr - s*aqr;  A[q][r] = s*apr + c*aqr;
          }
#pragma unroll
          for (int r = 0; r < 4; ++r) {
            float urp = U[r][p], urq = U[r][q];
            U[r][p] = c*urp - s*urq;  U[r][q] = s*urp + c*urq;
          }
        }
      }
    }
  }

  float wis[4];
#pragma unroll
  for (int b = 0; b < 4; ++b) {
    float w = A[b][b];
    if (w < 1e-12f) w = 1e-12f;
    wis[b] = rsqrtf(w);
  }

  float Wm[4][4];
#pragma unroll
  for (int a = 0; a < 4; ++a)
#pragma unroll
    for (int cc = 0; cc < 4; ++cc) {
      float acc = 0.0f;
#pragma unroll
      for (int b = 0; b < 4; ++b) acc += U[a][b] * wis[b] * U[cc][b];
      Wm[a][cc] = acc;
    }

  float G[4][4];
  G[0][0] = grr[d]; G[0][1] = G[1][0] = gri[d];
  G[0][2] = G[2][0] = grj[d]; G[0][3] = G[3][0] = grk[d];
  G[1][1] = gii[d]; G[1][2] = G[2][1] = gij[d];
  G[1][3] = G[3][1] = gik[d];
  G[2][2] = gjj[d]; G[2][3] = G[3][2] = gjk[d];
  G[3][3] = gkk[d];

  float M[4][4];
#pragma unroll
  for (int e = 0; e < 4; ++e)
#pragma unroll
    for (int cc = 0; cc < 4; ++cc) {
      float acc = 0.0f;
#pragma unroll
      for (int b = 0; b < 4; ++b) acc += G[e][b] * Wm[b][cc];
      M[e][cc] = acc;
      Mout[e*4 + cc] = acc;
    }

#pragma unroll
  for (int e = 0; e < 4; ++e) {
    float acc = beta[e*64 + d];
#pragma unroll
    for (int cc = 0; cc < 4; ++cc) acc -= M[e][cc] * (float)mu[cc];
    offout[e] = acc;
  }
}

// ---------------------------------------------------------------------------
// Fused cooperative kernel: reduce -> grid.sync -> sum -> grid.sync ->
// per-block solve (redundant) -> apply. One dispatch, full counters.
// ---------------------------------------------------------------------------
__global__ __launch_bounds__(256, 4) void hbn_fused(
    const float* __restrict__ x, const float* __restrict__ beta,
    const float* __restrict__ grr, const float* __restrict__ gri,
    const float* __restrict__ grj, const float* __restrict__ grk,
    const float* __restrict__ gii, const float* __restrict__ gij,
    const float* __restrict__ gik, const float* __restrict__ gjj,
    const float* __restrict__ gjk, const float* __restrict__ gkk,
    float* __restrict__ partial, double* __restrict__ Sg,
    float* __restrict__ out) {
  cg::grid_group grid = cg::this_grid();
  const int tid  = threadIdx.x;
  const int lane = tid & 63;
  const int wib  = tid >> 6;                       // wave in block (0..3)
  const int gw   = blockIdx.x * 4 + wib;           // global wave id
  const int nw   = FGRID * 4;                      // 4096 waves

  // ---- Phase 1: per-d partial statistics --------------------------------
  {
    float s0=0.f, s1=0.f, s2=0.f, s3=0.f;
    float q0=0.f,q1=0.f,q2=0.f,q3=0.f,q4=0.f,q5=0.f,q6=0.f,q7=0.f,q8=0.f,q9=0.f;

    for (int p = gw * 2; p < NPOS; p += nw * 2) {
      const float* b = x + (size_t)p * CCH + lane;
      float r0 = b[0],   i0 = b[64],  j0 = b[128], k0 = b[192];
      float r1 = b[256], i1 = b[320], j1 = b[384], k1 = b[448];
      s0 += r0 + r1; s1 += i0 + i1; s2 += j0 + j1; s3 += k0 + k1;
      q0 = fmaf(r0,r0, fmaf(r1,r1, q0));
      q1 = fmaf(r0,i0, fmaf(r1,i1, q1));
      q2 = fmaf(r0,j0, fmaf(r1,j1, q2));
      q3 = fmaf(r0,k0, fmaf(r1,k1, q3));
      q4 = fmaf(i0,i0, fmaf(i1,i1, q4));
      q5 = fmaf(i0,j0, fmaf(i1,j1, q5));
      q6 = fmaf(i0,k0, fmaf(i1,k1, q6));
      q7 = fmaf(j0,j0, fmaf(j1,j1, q7));
      q8 = fmaf(j0,k0, fmaf(j1,k1, q8));
      q9 = fmaf(k0,k0, fmaf(k1,k1, q9));
    }

    __shared__ float red[14][256];
    red[0][tid]=s0;  red[1][tid]=s1;  red[2][tid]=s2;  red[3][tid]=s3;
    red[4][tid]=q0;  red[5][tid]=q1;  red[6][tid]=q2;  red[7][tid]=q3;
    red[8][tid]=q4;  red[9][tid]=q5;  red[10][tid]=q6; red[11][tid]=q7;
    red[12][tid]=q8; red[13][tid]=q9;
    __syncthreads();
    if (tid < 64) {
      float* dst = partial + (size_t)blockIdx.x * 896;
#pragma unroll
      for (int q = 0; q < 14; ++q) {
        float v = red[q][tid] + red[q][tid+64] + red[q][tid+128] + red[q][tid+192];
        dst[q*64 + tid] = v;
      }
    }
  }
  grid.sync();

  // ---- Phase 2: sum partials. One wave per statistic o (896 of 4096). ---
  if (gw < 896) {
    double acc = 0.0;
#pragma unroll
    for (int m = 0; m < FGRID / 64; ++m)   // 16 scattered loads, independent
      acc += (double)partial[(size_t)(m * 64 + lane) * 896 + gw];
#pragma unroll
    for (int off = 32; off > 0; off >>= 1) acc += __shfl_down(acc, off);
    if (lane == 0) Sg[gw] = acc;
  }
  grid.sync();

  // ---- Phase 3: redundant per-block solve, then apply. ------------------
  __shared__ float Ms[64 * 16];
  __shared__ float offs[256];
  if (tid < 64) {
    float Mo[16], oo[4];
    solve_one(Sg, beta, grr, gri, grj, grk, gii, gij, gik, gjj, gjk, gkk,
              tid, Mo, oo);
#pragma unroll
    for (int c = 0; c < 16; ++c) Ms[tid*16 + c] = Mo[c];
#pragma unroll
    for (int e = 0; e < 4; ++e) offs[e*64 + tid] = oo[e];
  }
  __syncthreads();

  const float m0  = Ms[lane*16+0],  m1  = Ms[lane*16+1],  m2  = Ms[lane*16+2],  m3  = Ms[lane*16+3];
  const float m4  = Ms[lane*16+4],  m5  = Ms[lane*16+5],  m6  = Ms[lane*16+6],  m7  = Ms[lane*16+7];
  const float m8  = Ms[lane*16+8],  m9  = Ms[lane*16+9],  m10 = Ms[lane*16+10], m11 = Ms[lane*16+11];
  const float m12 = Ms[lane*16+12], m13 = Ms[lane*16+13], m14 = Ms[lane*16+14], m15 = Ms[lane*16+15];
  const float o0 = offs[lane], o1 = offs[64+lane], o2 = offs[128+lane], o3 = offs[192+lane];

  for (int p = gw * 2; p < NPOS; p += nw * 2) {
    const float* b = x + (size_t)p * CCH + lane;
    float r0 = b[0],   i0 = b[64],  j0 = b[128], k0 = b[192];
    float r1 = b[256], i1 = b[320], j1 = b[384], k1 = b[448];

    float ya0 = fmaf(m0, r0, fmaf(m1, i0, fmaf(m2, j0, fmaf(m3, k0, o0))));
    float ya1 = fmaf(m4, r0, fmaf(m5, i0, fmaf(m6, j0, fmaf(m7, k0, o1))));
    float ya2 = fmaf(m8, r0, fmaf(m9, i0, fmaf(m10,j0, fmaf(m11,k0, o2))));
    float ya3 = fmaf(m12,r0, fmaf(m13,i0, fmaf(m14,j0, fmaf(m15,k0, o3))));
    float yb0 = fmaf(m0, r1, fmaf(m1, i1, fmaf(m2, j1, fmaf(m3, k1, o0))));
    float yb1 = fmaf(m4, r1, fmaf(m5, i1, fmaf(m6, j1, fmaf(m7, k1, o1))));
    float yb2 = fmaf(m8, r1, fmaf(m9, i1, fmaf(m10,j1, fmaf(m11,k1, o2))));
    float yb3 = fmaf(m12,r1, fmaf(m13,i1, fmaf(m14,j1, fmaf(m15,k1, o3))));

    ya0 = ya0 > 0.f ? ya0 : (__expf(ya0) - 1.f);
    ya1 = ya1 > 0.f ? ya1 : (__expf(ya1) - 1.f);
    ya2 = ya2 > 0.f ? ya2 : (__expf(ya2) - 1.f);
    ya3 = ya3 > 0.f ? ya3 : (__expf(ya3) - 1.f);
    yb0 = yb0 > 0.f ? yb0 : (__expf(yb0) - 1.f);
    yb1 = yb1 > 0.f ? yb1 : (__expf(yb1) - 1.f);
    yb2 = yb2 > 0.f ? yb2 : (__expf(yb2) - 1.f);
    yb3 = yb3 > 0.f ? yb3 : (__expf(yb3) - 1.f);

    float* ob = out + (size_t)p * CCH + lane;
    __builtin_nontemporal_store(ya0, ob + 0);
    __builtin_nontemporal_store(ya1, ob + 64);
    __builtin_nontemporal_store(ya2, ob + 128);
    __builtin_nontemporal_store(ya3, ob + 192);
    __builtin_nontemporal_store(yb0, ob + 256);
    __builtin_nontemporal_store(yb1, ob + 320);
    __builtin_nontemporal_store(yb2, ob + 384);
    __builtin_nontemporal_store(yb3, ob + 448);
  }
}

// ---------------------------------------------------------------------------
// Fallback path (R3 structure: 71 µs): reduce / sum / solve / apply.
// ---------------------------------------------------------------------------
static constexpr int NBF = 128;

__global__ __launch_bounds__(1024) void fb_reduce(const float* __restrict__ x,
                                                  float* __restrict__ partial) {
  const int tid  = threadIdx.x;
  const int lane = tid & 63;
  const int gw   = blockIdx.x * 16 + (tid >> 6);
  const int nw   = NBF * 16;

  float s0=0.f, s1=0.f, s2=0.f, s3=0.f;
  float q0=0.f,q1=0.f,q2=0.f,q3=0.f,q4=0.f,q5=0.f,q6=0.f,q7=0.f,q8=0.f,q9=0.f;
  for (int p = gw * 2; p < NPOS; p += nw * 2) {
    const float* b = x + (size_t)p * CCH + lane;
    float r0 = b[0],   i0 = b[64],  j0 = b[128], k0 = b[192];
    float r1 = b[256], i1 = b[320], j1 = b[384], k1 = b[448];
    s0 += r0 + r1; s1 += i0 + i1; s2 += j0 + j1; s3 += k0 + k1;
    q0 = fmaf(r0,r0, fmaf(r1,r1, q0));
    q1 = fmaf(r0,i0, fmaf(r1,i1, q1));
    q2 = fmaf(r0,j0, fmaf(r1,j1, q2));
    q3 = fmaf(r0,k0, fmaf(r1,k1, q3));
    q4 = fmaf(i0,i0, fmaf(i1,i1, q4));
    q5 = fmaf(i0,j0, fmaf(i1,j1, q5));
    q6 = fmaf(i0,k0, fmaf(i1,k1, q6));
    q7 = fmaf(j0,j0, fmaf(j1,j1, q7));
    q8 = fmaf(j0,k0, fmaf(j1,k1, q8));
    q9 = fmaf(k0,k0, fmaf(k1,k1, q9));
  }
  __shared__ float red[14][1024];
  red[0][tid]=s0;  red[1][tid]=s1;  red[2][tid]=s2;  red[3][tid]=s3;
  red[4][tid]=q0;  red[5][tid]=q1;  red[6][tid]=q2;  red[7][tid]=q3;
  red[8][tid]=q4;  red[9][tid]=q5;  red[10][tid]=q6; red[11][tid]=q7;
  red[12][tid]=q8; red[13][tid]=q9;
  __syncthreads();
  if (tid < 64) {
    float* dst = partial + (size_t)blockIdx.x * 896;
#pragma unroll
    for (int q = 0; q < 14; ++q) {
      float v = 0.f;
#pragma unroll
      for (int w = 0; w < 16; ++w) v += red[q][tid + 64*w];
      dst[q*64 + tid] = v;
    }
  }
}

__global__ __launch_bounds__(256) void fb_sum(const float* __restrict__ partial,
                                              double* __restrict__ S) {
  const int t = blockIdx.x * 256 + threadIdx.x;
  if (t >= 896) return;
  double acc = 0.0;
#pragma unroll 8
  for (int b = 0; b < NBF; ++b) acc += (double)partial[(size_t)b * 896 + t];
  S[t] = acc;
}

__global__ void fb_solve(const double* __restrict__ S, const float* __restrict__ beta,
                         const float* __restrict__ grr, const float* __restrict__ gri,
                         const float* __restrict__ grj, const float* __restrict__ grk,
                         const float* __restrict__ gii, const float* __restrict__ gij,
                         const float* __restrict__ gik, const float* __restrict__ gjj,
                         const float* __restrict__ gjk, const float* __restrict__ gkk,
                         float* __restrict__ Mmat, float* __restrict__ offv) {
  const int d = threadIdx.x;
  float Mo[16], oo[4];
  solve_one(S, beta, grr, gri, grj, grk, gii, gij, gik, gjj, gjk, gkk, d, Mo, oo);
#pragma unroll
  for (int c = 0; c < 16; ++c) Mmat[d*16 + c] = Mo[c];
#pragma unroll
  for (int e = 0; e < 4; ++e) offv[e*64 + d] = oo[e];
}

__global__ __launch_bounds__(256) void fb_apply(const float* __restrict__ x,
                                                const float* __restrict__ Mmat,
                                                const float* __restrict__ offv,
                                                float* __restrict__ out) {
  const int tid  = threadIdx.x;
  const int lane = tid & 63;
  const int gw   = blockIdx.x * 4 + (tid >> 6);
  const int nw   = gridDim.x * 4;

  const float m0  = Mmat[lane*16+0],  m1  = Mmat[lane*16+1],  m2  = Mmat[lane*16+2],  m3  = Mmat[lane*16+3];
  const float m4  = Mmat[lane*16+4],  m5  = Mmat[lane*16+5],  m6  = Mmat[lane*16+6],  m7  = Mmat[lane*16+7];
  const float m8  = Mmat[lane*16+8],  m9  = Mmat[lane*16+9],  m10 = Mmat[lane*16+10], m11 = Mmat[lane*16+11];
  const float m12 = Mmat[lane*16+12], m13 = Mmat[lane*16+13], m14 = Mmat[lane*16+14], m15 = Mmat[lane*16+15];
  const float o0 = offv[lane], o1 = offv[64+lane], o2 = offv[128+lane], o3 = offv[192+lane];

  for (int p = gw * 2; p < NPOS; p += nw * 2) {
    const float* b = x + (size_t)p * CCH + lane;
    float r0 = b[0],   i0 = b[64],  j0 = b[128], k0 = b[192];
    float r1 = b[256], i1 = b[320], j1 = b[384], k1 = b[448];
    float ya0 = fmaf(m0, r0, fmaf(m1, i0, fmaf(m2, j0, fmaf(m3, k0, o0))));
    float ya1 = fmaf(m4, r0, fmaf(m5, i0, fmaf(m6, j0, fmaf(m7, k0, o1))));
    float ya2 = fmaf(m8, r0, fmaf(m9, i0, fmaf(m10,j0, fmaf(m11,k0, o2))));
    float ya3 = fmaf(m12,r0, fmaf(m13,i0, fmaf(m14,j0, fmaf(m15,k0, o3))));
    float yb0 = fmaf(m0, r1, fmaf(m1, i1, fmaf(m2, j1, fmaf(m3, k1, o0))));
    float yb1 = fmaf(m4, r1, fmaf(m5, i1, fmaf(m6, j1, fmaf(m7, k1, o1))));
    float yb2 = fmaf(m8, r1, fmaf(m9, i1, fmaf(m10,j1, fmaf(m11,k1, o2))));
    float yb3 = fmaf(m12,r1, fmaf(m13,i1, fmaf(m14,j1, fmaf(m15,k1, o3))));
    ya0 = ya0 > 0.f ? ya0 : (__expf(ya0) - 1.f);
    ya1 = ya1 > 0.f ? ya1 : (__expf(ya1) - 1.f);
    ya2 = ya2 > 0.f ? ya2 : (__expf(ya2) - 1.f);
    ya3 = ya3 > 0.f ? ya3 : (__expf(ya3) - 1.f);
    yb0 = yb0 > 0.f ? yb0 : (__expf(yb0) - 1.f);
    yb1 = yb1 > 0.f ? yb1 : (__expf(yb1) - 1.f);
    yb2 = yb2 > 0.f ? yb2 : (__expf(yb2) - 1.f);
    yb3 = yb3 > 0.f ? yb3 : (__expf(yb3) - 1.f);
    float* ob = out + (size_t)p * CCH + lane;
    __builtin_nontemporal_store(ya0, ob + 0);
    __builtin_nontemporal_store(ya1, ob + 64);
    __builtin_nontemporal_store(ya2, ob + 128);
    __builtin_nontemporal_store(ya3, ob + 192);
    __builtin_nontemporal_store(yb0, ob + 256);
    __builtin_nontemporal_store(yb1, ob + 320);
    __builtin_nontemporal_store(yb2, ob + 384);
    __builtin_nontemporal_store(yb3, ob + 448);
  }
}

extern "C" void kernel_launch(void* const* d_in, const int* in_sizes, int n_in,
                              void* d_out, int out_size, void* d_ws, size_t ws_size,
                              hipStream_t stream) {
  (void)in_sizes; (void)n_in; (void)out_size;
  const float* x    = (const float*)d_in[0];
  const float* beta = (const float*)d_in[1];
  const float* grr  = (const float*)d_in[2];
  const float* gri  = (const float*)d_in[3];
  const float* grj  = (const float*)d_in[4];
  const float* grk  = (const float*)d_in[5];
  const float* gii  = (const float*)d_in[6];
  const float* gij  = (const float*)d_in[7];
  const float* gik  = (const float*)d_in[8];
  const float* gjj  = (const float*)d_in[9];
  const float* gjk  = (const float*)d_in[10];
  const float* gkk  = (const float*)d_in[11];
  float* out = (float*)d_out;

  double* S      = (double*)d_ws;                   // 896 f64
  float*  Mmat   = (float*)((char*)d_ws + 7168);    // fallback
  float*  offv   = (float*)((char*)d_ws + 11264);   // fallback
  float*  partial= (float*)((char*)d_ws + 12288);

  const size_t need = 12288 + (size_t)FGRID * 896 * sizeof(float);
  bool fused_ok = (ws_size >= need);

  if (fused_ok) {
    void* args[] = { (void*)&x, (void*)&beta,
                     (void*)&grr, (void*)&gri, (void*)&grj, (void*)&grk,
                     (void*)&gii, (void*)&gij, (void*)&gik, (void*)&gjj,
                     (void*)&gjk, (void*)&gkk,
                     (void*)&partial, (void*)&S, (void*)&out };
    hipError_t err = hipLaunchCooperativeKernel((const void*)hbn_fused,
                                                dim3(FGRID), dim3(256),
                                                args, 0, stream);
    if (err == hipSuccess) return;
    (void)hipGetLastError();   // clear sticky error, fall through to fallback
  }

  fb_reduce<<<NBF, 1024, 0, stream>>>(x, partial);
  fb_sum<<<4, 256, 0, stream>>>(partial, S);
  fb_solve<<<1, 64, 0, stream>>>(S, beta, grr, gri, grj, grk,
                                 gii, gij, gik, gjj, gjk, gkk, Mmat, offv);
  fb_apply<<<2048, 256, 0, stream>>>(x, Mmat, offv, out);
}

// Round 7
// 91.295 us; speedup vs baseline: 3.1473x; 3.1473x over previous
//
#include <hip/hip_runtime.h>
#include <math.h>

static constexpr int NPOS  = 32 * 56 * 56;   // 100352 positions
static constexpr int NQUAD = NPOS / 4;       // 25088 position-quads
static constexpr int CCH   = 256;
static constexpr int RB    = 512;            // reduce blocks (256 thr = 2048 waves)
static constexpr int AB    = 1024;           // apply blocks
static constexpr double EPSV = 1e-6;

typedef float f32x4 __attribute__((ext_vector_type(4)));   // native vector: OK for NT builtins

// ws layout (bytes):
//   S      [896] f64        @ 0       (7168 B)
//   Mt     [16][64] f32     @ 7168    (4096 B)  transposed: Mt[coeff*64+d]
//   offv   [4][64] f32      @ 11264   (1024 B)
//   partial[RB][896] f32    @ 12288   (512*896*4 = 1835008 B)

__device__ __forceinline__ float eluf(float v) {
  return v > 0.f ? v : (__expf(v) - 1.f);
}

// ---------------------------------------------------------------------------
// Kernel 1: per-d statistics, float4 loads (16 B/lane — G13).
// lane = (psub = lane>>4: position within quad, dquad = lane&15: 4 d's).
// Per iter a wave covers 4 positions x 1 KB, fully coalesced dwordx4.
// 56 f32 accumulators per lane; shfl_xor fold over psub; LDS block combine.
// stats: 0..3 = sums(r,i,j,k); 4..13 = rr,ri,rj,rk,ii,ij,ik,jj,jk,kk
// ---------------------------------------------------------------------------
__global__ __launch_bounds__(256) void hbn_reduce(const float* __restrict__ x,
                                                  float* __restrict__ partial) {
  const int tid   = threadIdx.x;
  const int lane  = tid & 63;
  const int wib   = tid >> 6;                 // wave in block (0..3)
  const int psub  = lane >> 4;                // 0..3
  const int dquad = lane & 15;                // 0..15
  const int gw    = blockIdx.x * 4 + wib;
  const int nw    = RB * 4;                   // 2048 waves

  float acc[14][4];
#pragma unroll
  for (int s = 0; s < 14; ++s)
#pragma unroll
    for (int t = 0; t < 4; ++t) acc[s][t] = 0.f;

  for (int pq = gw; pq < NQUAD; pq += nw) {
    const float* b = x + (size_t)(pq * 4 + psub) * CCH + dquad * 4;
    const f32x4 r4 = *reinterpret_cast<const f32x4*>(b);
    const f32x4 i4 = *reinterpret_cast<const f32x4*>(b + 64);
    const f32x4 j4 = *reinterpret_cast<const f32x4*>(b + 128);
    const f32x4 k4 = *reinterpret_cast<const f32x4*>(b + 192);
#pragma unroll
    for (int t = 0; t < 4; ++t) {
      const float r = r4[t], i = i4[t], j = j4[t], k = k4[t];
      acc[0][t] += r;  acc[1][t] += i;  acc[2][t] += j;  acc[3][t] += k;
      acc[4][t]  = fmaf(r, r, acc[4][t]);
      acc[5][t]  = fmaf(r, i, acc[5][t]);
      acc[6][t]  = fmaf(r, j, acc[6][t]);
      acc[7][t]  = fmaf(r, k, acc[7][t]);
      acc[8][t]  = fmaf(i, i, acc[8][t]);
      acc[9][t]  = fmaf(i, j, acc[9][t]);
      acc[10][t] = fmaf(i, k, acc[10][t]);
      acc[11][t] = fmaf(j, j, acc[11][t]);
      acc[12][t] = fmaf(j, k, acc[12][t]);
      acc[13][t] = fmaf(k, k, acc[13][t]);
    }
  }

  // fold across psub (lanes differing in bits 4,5 share dquad)
#pragma unroll
  for (int s = 0; s < 14; ++s)
#pragma unroll
    for (int t = 0; t < 4; ++t) {
      float v = acc[s][t];
      v += __shfl_xor(v, 16);
      v += __shfl_xor(v, 32);
      acc[s][t] = v;
    }

  __shared__ float lds[4][896];     // [wave][stat*64 + d]
  if (lane < 16) {
#pragma unroll
    for (int s = 0; s < 14; ++s)
#pragma unroll
      for (int t = 0; t < 4; ++t)
        lds[wib][s * 64 + dquad * 4 + t] = acc[s][t];
  }
  __syncthreads();

  float* dst = partial + (size_t)blockIdx.x * 896;
  for (int idx = tid; idx < 896; idx += 256)
    dst[idx] = lds[0][idx] + lds[1][idx] + lds[2][idx] + lds[3][idx];
}

// ---------------------------------------------------------------------------
// Kernel 2: sum partials over blocks (coalesced rows), f64 accumulate.
// ---------------------------------------------------------------------------
__global__ __launch_bounds__(256) void hbn_sum(const float* __restrict__ partial,
                                               double* __restrict__ S) {
  const int t = blockIdx.x * 256 + threadIdx.x;
  if (t >= 896) return;
  double acc = 0.0;
#pragma unroll 8
  for (int b = 0; b < RB; ++b) acc += (double)partial[(size_t)b * 896 + t];
  S[t] = acc;
}

// ---------------------------------------------------------------------------
// Kernel 3: per-d 4x4 covariance -> V^{-1/2} (f32 Jacobi) -> fold G, mean,
// beta into Mt (TRANSPOSED: Mt[(e*4+c)*64 + d]) + offv[e*64+d].
// ---------------------------------------------------------------------------
__global__ void hbn_solve(const double* __restrict__ S,
                          const float* __restrict__ beta,
                          const float* __restrict__ grr, const float* __restrict__ gri,
                          const float* __restrict__ grj, const float* __restrict__ grk,
                          const float* __restrict__ gii, const float* __restrict__ gij,
                          const float* __restrict__ gik, const float* __restrict__ gjj,
                          const float* __restrict__ gjk, const float* __restrict__ gkk,
                          float* __restrict__ Mt, float* __restrict__ offv) {
  const int d = threadIdx.x;   // 0..63
  const double invM = 1.0 / (double)NPOS;

  double mu[4];
  mu[0] = S[0*64+d]*invM; mu[1] = S[1*64+d]*invM;
  mu[2] = S[2*64+d]*invM; mu[3] = S[3*64+d]*invM;

  float A[4][4];
  A[0][0] = (float)(S[4*64+d]*invM  - mu[0]*mu[0] + EPSV);
  A[0][1] = A[1][0] = (float)(S[5*64+d]*invM  - mu[0]*mu[1]);
  A[0][2] = A[2][0] = (float)(S[6*64+d]*invM  - mu[0]*mu[2]);
  A[0][3] = A[3][0] = (float)(S[7*64+d]*invM  - mu[0]*mu[3]);
  A[1][1] = (float)(S[8*64+d]*invM  - mu[1]*mu[1] + EPSV);
  A[1][2] = A[2][1] = (float)(S[9*64+d]*invM  - mu[1]*mu[2]);
  A[1][3] = A[3][1] = (float)(S[10*64+d]*invM - mu[1]*mu[3]);
  A[2][2] = (float)(S[11*64+d]*invM - mu[2]*mu[2] + EPSV);
  A[2][3] = A[3][2] = (float)(S[12*64+d]*invM - mu[2]*mu[3]);
  A[3][3] = (float)(S[13*64+d]*invM - mu[3]*mu[3] + EPSV);

  float U[4][4] = {{1,0,0,0},{0,1,0,0},{0,0,1,0},{0,0,0,1}};

#pragma unroll 1
  for (int sweep = 0; sweep < 6; ++sweep) {
#pragma unroll
    for (int p = 0; p < 3; ++p) {
#pragma unroll
      for (int q = p + 1; q < 4; ++q) {
        float apq = A[p][q];
        if (fabsf(apq) > 1e-30f) {
          float theta = (A[q][q] - A[p][p]) / (2.0f * apq);
          float t = 1.0f / (fabsf(theta) + sqrtf(fmaf(theta, theta, 1.0f)));
          if (theta < 0.0f) t = -t;
          float c = rsqrtf(fmaf(t, t, 1.0f));
          float s = t * c;
#pragma unroll
          for (int r = 0; r < 4; ++r) {
            float arp = A[r][p], arq = A[r][q];
            A[r][p] = c*arp - s*arq;  A[r][q] = s*arp + c*arq;
          }
#pragma unroll
          for (int r = 0; r < 4; ++r) {
            float apr = A[p][r], aqr = A[q][r];
            A[p][r] = c*apr - s*aqr;  A[q][r] = s*apr + c*aqr;
          }
#pragma unroll
          for (int r = 0; r < 4; ++r) {
            float urp = U[r][p], urq = U[r][q];
            U[r][p] = c*urp - s*urq;  U[r][q] = s*urp + c*urq;
          }
        }
      }
    }
  }

  float wis[4];
#pragma unroll
  for (int b = 0; b < 4; ++b) {
    float w = A[b][b];
    if (w < 1e-12f) w = 1e-12f;
    wis[b] = rsqrtf(w);
  }

  float Wm[4][4];
#pragma unroll
  for (int a = 0; a < 4; ++a)
#pragma unroll
    for (int cc = 0; cc < 4; ++cc) {
      float acc = 0.0f;
#pragma unroll
      for (int b = 0; b < 4; ++b) acc += U[a][b] * wis[b] * U[cc][b];
      Wm[a][cc] = acc;
    }

  float G[4][4];
  G[0][0] = grr[d]; G[0][1] = G[1][0] = gri[d];
  G[0][2] = G[2][0] = grj[d]; G[0][3] = G[3][0] = grk[d];
  G[1][1] = gii[d]; G[1][2] = G[2][1] = gij[d];
  G[1][3] = G[3][1] = gik[d];
  G[2][2] = gjj[d]; G[2][3] = G[3][2] = gjk[d];
  G[3][3] = gkk[d];

  float M[4][4];
#pragma unroll
  for (int e = 0; e < 4; ++e)
#pragma unroll
    for (int cc = 0; cc < 4; ++cc) {
      float acc = 0.0f;
#pragma unroll
      for (int b = 0; b < 4; ++b) acc += G[e][b] * Wm[b][cc];
      M[e][cc] = acc;
      Mt[(e*4 + cc)*64 + d] = acc;      // transposed for float4 coeff loads
    }

#pragma unroll
  for (int e = 0; e < 4; ++e) {
    float acc = beta[e*64 + d];
#pragma unroll
    for (int cc = 0; cc < 4; ++cc) acc -= M[e][cc] * (float)mu[cc];
    offv[e*64 + d] = acc;
  }
}

// ---------------------------------------------------------------------------
// Kernel 4: y = ELU(M x + off), float4 in / float4 NT out.
// Coefficients hoisted to registers (16x f32x4 + 4x f32x4 per lane).
// ---------------------------------------------------------------------------
__global__ __launch_bounds__(256) void hbn_apply(const float* __restrict__ x,
                                                 const float* __restrict__ Mt,
                                                 const float* __restrict__ offv,
                                                 float* __restrict__ out) {
  const int tid   = threadIdx.x;
  const int lane  = tid & 63;
  const int psub  = lane >> 4;
  const int dquad = lane & 15;
  const int gw    = blockIdx.x * 4 + (tid >> 6);
  const int nw    = AB * 4;                    // 4096 waves

  f32x4 mc[16];
#pragma unroll
  for (int c = 0; c < 16; ++c)
    mc[c] = *reinterpret_cast<const f32x4*>(Mt + c * 64 + dquad * 4);
  f32x4 ob[4];
#pragma unroll
  for (int e = 0; e < 4; ++e)
    ob[e] = *reinterpret_cast<const f32x4*>(offv + e * 64 + dquad * 4);

  for (int pq = gw; pq < NQUAD; pq += nw) {
    const size_t pbase = (size_t)(pq * 4 + psub) * CCH + dquad * 4;
    const float* b = x + pbase;
    const f32x4 r4 = *reinterpret_cast<const f32x4*>(b);
    const f32x4 i4 = *reinterpret_cast<const f32x4*>(b + 64);
    const f32x4 j4 = *reinterpret_cast<const f32x4*>(b + 128);
    const f32x4 k4 = *reinterpret_cast<const f32x4*>(b + 192);

    float* o = out + pbase;
#pragma unroll
    for (int e = 0; e < 4; ++e) {
      f32x4 y;
#pragma unroll
      for (int t = 0; t < 4; ++t)
        y[t] = fmaf(mc[e*4][t], r4[t],
               fmaf(mc[e*4+1][t], i4[t],
               fmaf(mc[e*4+2][t], j4[t],
               fmaf(mc[e*4+3][t], k4[t], ob[e][t]))));
#pragma unroll
      for (int t = 0; t < 4; ++t) y[t] = eluf(y[t]);
      __builtin_nontemporal_store(y, reinterpret_cast<f32x4*>(o + e * 64));
    }
  }
}

extern "C" void kernel_launch(void* const* d_in, const int* in_sizes, int n_in,
                              void* d_out, int out_size, void* d_ws, size_t ws_size,
                              hipStream_t stream) {
  (void)in_sizes; (void)n_in; (void)out_size; (void)ws_size;
  const float* x    = (const float*)d_in[0];
  const float* beta = (const float*)d_in[1];
  const float* grr  = (const float*)d_in[2];
  const float* gri  = (const float*)d_in[3];
  const float* grj  = (const float*)d_in[4];
  const float* grk  = (const float*)d_in[5];
  const float* gii  = (const float*)d_in[6];
  const float* gij  = (const float*)d_in[7];
  const float* gik  = (const float*)d_in[8];
  const float* gjj  = (const float*)d_in[9];
  const float* gjk  = (const float*)d_in[10];
  const float* gkk  = (const float*)d_in[11];
  float* out = (float*)d_out;

  double* S      = (double*)d_ws;                   // 896 f64
  float*  Mt     = (float*)((char*)d_ws + 7168);    // 16x64 f32 transposed
  float*  offv   = (float*)((char*)d_ws + 11264);   // 4x64 f32
  float*  partial= (float*)((char*)d_ws + 12288);   // RB*896 f32

  hbn_reduce<<<RB, 256, 0, stream>>>(x, partial);
  hbn_sum<<<4, 256, 0, stream>>>(partial, S);
  hbn_solve<<<1, 64, 0, stream>>>(S, beta, grr, gri, grj, grk,
                                  gii, gij, gik, gjj, gjk, gkk, Mt, offv);
  hbn_apply<<<AB, 256, 0, stream>>>(x, Mt, offv, out);
}

// Round 8
// 75.986 us; speedup vs baseline: 3.7814x; 1.2015x over previous
//
#include <hip/hip_runtime.h>
#include <math.h>

static constexpr int NPOS = 32 * 56 * 56;   // 100352 positions
static constexpr int CCH  = 256;
static constexpr int RB   = 512;            // reduce blocks (2048 waves; NPOS/2048 = 49 exact)
static constexpr int ABLK = 2048;           // apply blocks (8192 waves)
static constexpr double EPSV = 1e-6;

typedef float f32x4 __attribute__((ext_vector_type(4)));

// ws layout (bytes):
//   S      [896] f64      @ 0       (7168 B)
//   Mt     [16][64] f32   @ 7168    (4096 B)   Mt[(e*4+c)*64 + d]
//   offv   [4][64] f32    @ 11264   (1024 B)
//   partial[RB][896] f32  @ 12288   (1835008 B)

__device__ __forceinline__ float eluf(float v) {
  return v > 0.f ? v : (__expf(v) - 1.f);
}

// ---------------------------------------------------------------------------
// Kernel 1: reduce. One wave-iteration = ONE position = 1KB CONTIGUOUS
// (lane l -> bytes 16l..16l+15: the m13 6.3TB/s pattern). Per-wave LDS
// transpose (write b128, 4 broadcast-read b128), no barriers needed.
// Every lane accumulates all 14 stats for its d-quad (lane&15); lane-quads
// hold identical values so lanes 0-15 carry the wave result.
// stats: 0..3 sums(r,i,j,k); 4..13 rr,ri,rj,rk,ii,ij,ik,jj,jk,kk
// ---------------------------------------------------------------------------
__global__ __launch_bounds__(256) void hbn_reduce(const float* __restrict__ x,
                                                  float* __restrict__ partial) {
  const int tid  = threadIdx.x;
  const int lane = tid & 63;
  const int wib  = tid >> 6;
  const int dq   = lane & 15;
  const int gw   = blockIdx.x * 4 + wib;
  const int nw   = RB * 4;                  // 2048; 100352/2048 = 49 exact

  __shared__ float stage[4][256];           // 1KB per wave
  __shared__ float outs[4][896];
  float* st = &stage[wib][0];

  float acc[14][4];
#pragma unroll
  for (int s = 0; s < 14; ++s)
#pragma unroll
    for (int t = 0; t < 4; ++t) acc[s][t] = 0.f;

  for (int p = gw; p < NPOS; p += nw) {
    const f32x4 v = *reinterpret_cast<const f32x4*>(x + (size_t)p * CCH + lane * 4);
    *reinterpret_cast<f32x4*>(st + lane * 4) = v;
    const f32x4 r4 = *reinterpret_cast<const f32x4*>(st + 0   + dq * 4);
    const f32x4 i4 = *reinterpret_cast<const f32x4*>(st + 64  + dq * 4);
    const f32x4 j4 = *reinterpret_cast<const f32x4*>(st + 128 + dq * 4);
    const f32x4 k4 = *reinterpret_cast<const f32x4*>(st + 192 + dq * 4);
#pragma unroll
    for (int t = 0; t < 4; ++t) {
      const float r = r4[t], i = i4[t], j = j4[t], k = k4[t];
      acc[0][t] += r;  acc[1][t] += i;  acc[2][t] += j;  acc[3][t] += k;
      acc[4][t]  = fmaf(r, r, acc[4][t]);
      acc[5][t]  = fmaf(r, i, acc[5][t]);
      acc[6][t]  = fmaf(r, j, acc[6][t]);
      acc[7][t]  = fmaf(r, k, acc[7][t]);
      acc[8][t]  = fmaf(i, i, acc[8][t]);
      acc[9][t]  = fmaf(i, j, acc[9][t]);
      acc[10][t] = fmaf(i, k, acc[10][t]);
      acc[11][t] = fmaf(j, j, acc[11][t]);
      acc[12][t] = fmaf(j, k, acc[12][t]);
      acc[13][t] = fmaf(k, k, acc[13][t]);
    }
  }

  if (lane < 16) {
#pragma unroll
    for (int s = 0; s < 14; ++s)
#pragma unroll
      for (int t = 0; t < 4; ++t)
        outs[wib][s * 64 + dq * 4 + t] = acc[s][t];
  }
  __syncthreads();
  float* dst = partial + (size_t)blockIdx.x * 896;
  for (int idx = tid; idx < 896; idx += 256)
    dst[idx] = outs[0][idx] + outs[1][idx] + outs[2][idx] + outs[3][idx];
}

// ---------------------------------------------------------------------------
// Kernel 2: sum partials. One wave per statistic (896 blocks), 8 loads/lane,
// f64 shfl reduce. Parallel & latency-tolerant.
// ---------------------------------------------------------------------------
__global__ __launch_bounds__(64) void hbn_sum(const float* __restrict__ partial,
                                              double* __restrict__ S) {
  const int s = blockIdx.x;       // 0..895
  const int t = threadIdx.x;      // 0..63
  double a = 0.0;
#pragma unroll
  for (int k = 0; k < RB / 64; ++k)
    a += (double)partial[(size_t)(k * 64 + t) * 896 + s];
#pragma unroll
  for (int off = 32; off; off >>= 1) a += __shfl_down(a, off);
  if (t == 0) S[s] = a;
}

// ---------------------------------------------------------------------------
// Kernel 3: per-d 4x4 covariance -> V^{-1/2} (f32 Jacobi) -> fold G, mean,
// beta into Mt (Mt[(e*4+c)*64 + d]) + offv[e*64+d].
// ---------------------------------------------------------------------------
__global__ void hbn_solve(const double* __restrict__ S,
                          const float* __restrict__ beta,
                          const float* __restrict__ grr, const float* __restrict__ gri,
                          const float* __restrict__ grj, const float* __restrict__ grk,
                          const float* __restrict__ gii, const float* __restrict__ gij,
                          const float* __restrict__ gik, const float* __restrict__ gjj,
                          const float* __restrict__ gjk, const float* __restrict__ gkk,
                          float* __restrict__ Mt, float* __restrict__ offv) {
  const int d = threadIdx.x;   // 0..63
  const double invM = 1.0 / (double)NPOS;

  double mu[4];
  mu[0] = S[0*64+d]*invM; mu[1] = S[1*64+d]*invM;
  mu[2] = S[2*64+d]*invM; mu[3] = S[3*64+d]*invM;

  float A[4][4];
  A[0][0] = (float)(S[4*64+d]*invM  - mu[0]*mu[0] + EPSV);
  A[0][1] = A[1][0] = (float)(S[5*64+d]*invM  - mu[0]*mu[1]);
  A[0][2] = A[2][0] = (float)(S[6*64+d]*invM  - mu[0]*mu[2]);
  A[0][3] = A[3][0] = (float)(S[7*64+d]*invM  - mu[0]*mu[3]);
  A[1][1] = (float)(S[8*64+d]*invM  - mu[1]*mu[1] + EPSV);
  A[1][2] = A[2][1] = (float)(S[9*64+d]*invM  - mu[1]*mu[2]);
  A[1][3] = A[3][1] = (float)(S[10*64+d]*invM - mu[1]*mu[3]);
  A[2][2] = (float)(S[11*64+d]*invM - mu[2]*mu[2] + EPSV);
  A[2][3] = A[3][2] = (float)(S[12*64+d]*invM - mu[2]*mu[3]);
  A[3][3] = (float)(S[13*64+d]*invM - mu[3]*mu[3] + EPSV);

  float U[4][4] = {{1,0,0,0},{0,1,0,0},{0,0,1,0},{0,0,0,1}};

#pragma unroll 1
  for (int sweep = 0; sweep < 6; ++sweep) {
#pragma unroll
    for (int p = 0; p < 3; ++p) {
#pragma unroll
      for (int q = p + 1; q < 4; ++q) {
        float apq = A[p][q];
        if (fabsf(apq) > 1e-30f) {
          float theta = (A[q][q] - A[p][p]) / (2.0f * apq);
          float t = 1.0f / (fabsf(theta) + sqrtf(fmaf(theta, theta, 1.0f)));
          if (theta < 0.0f) t = -t;
          float c = rsqrtf(fmaf(t, t, 1.0f));
          float s = t * c;
#pragma unroll
          for (int r = 0; r < 4; ++r) {
            float arp = A[r][p], arq = A[r][q];
            A[r][p] = c*arp - s*arq;  A[r][q] = s*arp + c*arq;
          }
#pragma unroll
          for (int r = 0; r < 4; ++r) {
            float apr = A[p][r], aqr = A[q][r];
            A[p][r] = c*apr - s*aqr;  A[q][r] = s*apr + c*aqr;
          }
#pragma unroll
          for (int r = 0; r < 4; ++r) {
            float urp = U[r][p], urq = U[r][q];
            U[r][p] = c*urp - s*urq;  U[r][q] = s*urp + c*urq;
          }
        }
      }
    }
  }

  float wis[4];
#pragma unroll
  for (int b = 0; b < 4; ++b) {
    float w = A[b][b];
    if (w < 1e-12f) w = 1e-12f;
    wis[b] = rsqrtf(w);
  }

  float Wm[4][4];
#pragma unroll
  for (int a = 0; a < 4; ++a)
#pragma unroll
    for (int cc = 0; cc < 4; ++cc) {
      float acc = 0.0f;
#pragma unroll
      for (int b = 0; b < 4; ++b) acc += U[a][b] * wis[b] * U[cc][b];
      Wm[a][cc] = acc;
    }

  float G[4][4];
  G[0][0] = grr[d]; G[0][1] = G[1][0] = gri[d];
  G[0][2] = G[2][0] = grj[d]; G[0][3] = G[3][0] = grk[d];
  G[1][1] = gii[d]; G[1][2] = G[2][1] = gij[d];
  G[1][3] = G[3][1] = gik[d];
  G[2][2] = gjj[d]; G[2][3] = G[3][2] = gjk[d];
  G[3][3] = gkk[d];

  float M[4][4];
#pragma unroll
  for (int e = 0; e < 4; ++e)
#pragma unroll
    for (int cc = 0; cc < 4; ++cc) {
      float acc = 0.0f;
#pragma unroll
      for (int b = 0; b < 4; ++b) acc += G[e][b] * Wm[b][cc];
      M[e][cc] = acc;
      Mt[(e*4 + cc)*64 + d] = acc;
    }

#pragma unroll
  for (int e = 0; e < 4; ++e) {
    float acc = beta[e*64 + d];
#pragma unroll
    for (int cc = 0; cc < 4; ++cc) acc -= M[e][cc] * (float)mu[cc];
    offv[e*64 + d] = acc;
  }
}

// ---------------------------------------------------------------------------
// Kernel 4: apply. Same contiguous-1KB-per-wave pattern + LDS transpose.
// Lane l's output channels 4l..4l+3 == component e=l>>4, d-quad l&15, so
// the computed f32x4 NT-stores contiguously. 5 coeff vectors per lane.
// ---------------------------------------------------------------------------
__global__ __launch_bounds__(256) void hbn_apply(const float* __restrict__ x,
                                                 const float* __restrict__ Mt,
                                                 const float* __restrict__ offv,
                                                 float* __restrict__ out) {
  const int tid  = threadIdx.x;
  const int lane = tid & 63;
  const int wib  = tid >> 6;
  const int dq   = lane & 15;
  const int e    = lane >> 4;
  const int gw   = blockIdx.x * 4 + wib;
  const int nw   = ABLK * 4;                 // 8192 waves

  __shared__ float stage[4][256];
  float* st = &stage[wib][0];

  f32x4 me[4];
#pragma unroll
  for (int c = 0; c < 4; ++c)
    me[c] = *reinterpret_cast<const f32x4*>(Mt + (e*4 + c)*64 + dq*4);
  const f32x4 ob = *reinterpret_cast<const f32x4*>(offv + e*64 + dq*4);

  for (int p = gw; p < NPOS; p += nw) {
    const f32x4 v = *reinterpret_cast<const f32x4*>(x + (size_t)p * CCH + lane * 4);
    *reinterpret_cast<f32x4*>(st + lane * 4) = v;
    const f32x4 r4 = *reinterpret_cast<const f32x4*>(st + 0   + dq * 4);
    const f32x4 i4 = *reinterpret_cast<const f32x4*>(st + 64  + dq * 4);
    const f32x4 j4 = *reinterpret_cast<const f32x4*>(st + 128 + dq * 4);
    const f32x4 k4 = *reinterpret_cast<const f32x4*>(st + 192 + dq * 4);

    f32x4 y;
#pragma unroll
    for (int t = 0; t < 4; ++t)
      y[t] = fmaf(me[0][t], r4[t],
             fmaf(me[1][t], i4[t],
             fmaf(me[2][t], j4[t],
             fmaf(me[3][t], k4[t], ob[t]))));
#pragma unroll
    for (int t = 0; t < 4; ++t) y[t] = eluf(y[t]);
    __builtin_nontemporal_store(y, reinterpret_cast<f32x4*>(out + (size_t)p * CCH + lane * 4));
  }
}

extern "C" void kernel_launch(void* const* d_in, const int* in_sizes, int n_in,
                              void* d_out, int out_size, void* d_ws, size_t ws_size,
                              hipStream_t stream) {
  (void)in_sizes; (void)n_in; (void)out_size; (void)ws_size;
  const float* x    = (const float*)d_in[0];
  const float* beta = (const float*)d_in[1];
  const float* grr  = (const float*)d_in[2];
  const float* gri  = (const float*)d_in[3];
  const float* grj  = (const float*)d_in[4];
  const float* grk  = (const float*)d_in[5];
  const float* gii  = (const float*)d_in[6];
  const float* gij  = (const float*)d_in[7];
  const float* gik  = (const float*)d_in[8];
  const float* gjj  = (const float*)d_in[9];
  const float* gjk  = (const float*)d_in[10];
  const float* gkk  = (const float*)d_in[11];
  float* out = (float*)d_out;

  double* S      = (double*)d_ws;                   // 896 f64
  float*  Mt     = (float*)((char*)d_ws + 7168);
  float*  offv   = (float*)((char*)d_ws + 11264);
  float*  partial= (float*)((char*)d_ws + 12288);   // RB*896 f32

  hbn_reduce<<<RB, 256, 0, stream>>>(x, partial);
  hbn_sum<<<896, 64, 0, stream>>>(partial, S);
  hbn_solve<<<1, 64, 0, stream>>>(S, beta, grr, gri, grj, grk,
                                  gii, gij, gik, gjj, gjk, gkk, Mt, offv);
  hbn_apply<<<ABLK, 256, 0, stream>>>(x, Mt, offv, out);
}

// Round 9
// 69.694 us; speedup vs baseline: 4.1228x; 1.0903x over previous
//
#include <hip/hip_runtime.h>
#include <math.h>

static constexpr int NPOS = 32 * 56 * 56;   // 100352 positions
static constexpr int CCH  = 256;
static constexpr int RB   = 1024;           // reduce blocks (4096 waves, 4 blocks/CU)
static constexpr int ABLK = 2048;           // apply blocks (8 blocks/CU)
static constexpr double EPSV = 1e-6;

typedef float f32x4 __attribute__((ext_vector_type(4)));

// ws layout (bytes):
//   S      [896] f64      @ 0       (7168 B)
//   partial[RB][896] f32  @ 12288   (RB*896*4 = 3670016 B)

__device__ __forceinline__ float eluf(float v) {
  return v > 0.f ? v : (__expf(v) - 1.f);
}

// ---------------------------------------------------------------------------
// Kernel 1: reduce. One wave-iteration = TWO positions, each 1KB contiguous
// (lane l -> bytes 16l..16l+15). Unroll-2 keeps 2 KB outstanding per wave;
// 1024 blocks = 4/CU = 16 waves/CU for MLP. Per-wave LDS transpose
// (wave-coherent, no barrier). Lanes with same (lane&15) hold identical
// accumulators; lanes 0-15 carry the wave result.
// stats: 0..3 sums(r,i,j,k); 4..13 rr,ri,rj,rk,ii,ij,ik,jj,jk,kk
// ---------------------------------------------------------------------------
__global__ __launch_bounds__(256) void hbn_reduce(const float* __restrict__ x,
                                                  float* __restrict__ partial) {
  const int tid  = threadIdx.x;
  const int lane = tid & 63;
  const int wib  = tid >> 6;
  const int dq   = lane & 15;
  const int gw   = blockIdx.x * 4 + wib;
  const int nw   = RB * 4;                  // 4096 waves

  __shared__ float stage[4][512];           // 2 KB per wave (2 positions)
  __shared__ float outs[4][896];
  float* st = &stage[wib][0];

  float acc[14][4];
#pragma unroll
  for (int s = 0; s < 14; ++s)
#pragma unroll
    for (int t = 0; t < 4; ++t) acc[s][t] = 0.f;

  for (int p0 = gw * 2; p0 < NPOS; p0 += nw * 2) {
    const f32x4 va = *reinterpret_cast<const f32x4*>(x + (size_t)p0 * CCH + lane * 4);
    const f32x4 vb = *reinterpret_cast<const f32x4*>(x + (size_t)(p0 + 1) * CCH + lane * 4);
    *reinterpret_cast<f32x4*>(st + lane * 4)       = va;
    *reinterpret_cast<f32x4*>(st + 256 + lane * 4) = vb;
#pragma unroll
    for (int h = 0; h < 2; ++h) {
      const f32x4 r4 = *reinterpret_cast<const f32x4*>(st + h*256 + 0   + dq * 4);
      const f32x4 i4 = *reinterpret_cast<const f32x4*>(st + h*256 + 64  + dq * 4);
      const f32x4 j4 = *reinterpret_cast<const f32x4*>(st + h*256 + 128 + dq * 4);
      const f32x4 k4 = *reinterpret_cast<const f32x4*>(st + h*256 + 192 + dq * 4);
#pragma unroll
      for (int t = 0; t < 4; ++t) {
        const float r = r4[t], i = i4[t], j = j4[t], k = k4[t];
        acc[0][t] += r;  acc[1][t] += i;  acc[2][t] += j;  acc[3][t] += k;
        acc[4][t]  = fmaf(r, r, acc[4][t]);
        acc[5][t]  = fmaf(r, i, acc[5][t]);
        acc[6][t]  = fmaf(r, j, acc[6][t]);
        acc[7][t]  = fmaf(r, k, acc[7][t]);
        acc[8][t]  = fmaf(i, i, acc[8][t]);
        acc[9][t]  = fmaf(i, j, acc[9][t]);
        acc[10][t] = fmaf(i, k, acc[10][t]);
        acc[11][t] = fmaf(j, j, acc[11][t]);
        acc[12][t] = fmaf(j, k, acc[12][t]);
        acc[13][t] = fmaf(k, k, acc[13][t]);
      }
    }
  }

  if (lane < 16) {
#pragma unroll
    for (int s = 0; s < 14; ++s)
#pragma unroll
      for (int t = 0; t < 4; ++t)
        outs[wib][s * 64 + dq * 4 + t] = acc[s][t];
  }
  __syncthreads();
  float* dst = partial + (size_t)blockIdx.x * 896;
  for (int idx = tid; idx < 896; idx += 256)
    dst[idx] = outs[0][idx] + outs[1][idx] + outs[2][idx] + outs[3][idx];
}

// ---------------------------------------------------------------------------
// Kernel 2: sum partials. Wave = one statistic (896 waves over 224 blocks);
// 16 scattered L2/L3 loads per lane, f64 shfl reduce. Latency-tolerant.
// ---------------------------------------------------------------------------
__global__ __launch_bounds__(256) void hbn_sum(const float* __restrict__ partial,
                                               double* __restrict__ S) {
  const int lane = threadIdx.x & 63;
  const int s    = blockIdx.x * 4 + (threadIdx.x >> 6);
  if (s >= 896) return;
  double a = 0.0;
#pragma unroll
  for (int k = 0; k < RB / 64; ++k)
    a += (double)partial[(size_t)(k * 64 + lane) * 896 + s];
#pragma unroll
  for (int off = 32; off; off >>= 1) a += __shfl_down(a, off);
  if (lane == 0) S[s] = a;
}

// ---------------------------------------------------------------------------
// Solve one d: S sums -> cov -> f32 Jacobi -> M = G*V^{-1/2}, off = beta-M*mu
// ---------------------------------------------------------------------------
__device__ __forceinline__ void solve_one(const double* __restrict__ S,
                                          const float* __restrict__ beta,
                                          const float* __restrict__ grr, const float* __restrict__ gri,
                                          const float* __restrict__ grj, const float* __restrict__ grk,
                                          const float* __restrict__ gii, const float* __restrict__ gij,
                                          const float* __restrict__ gik, const float* __restrict__ gjj,
                                          const float* __restrict__ gjk, const float* __restrict__ gkk,
                                          int d, float* Mout /*16*/, float* offout /*4*/) {
  const double invM = 1.0 / (double)NPOS;
  double mu[4];
  mu[0] = S[0*64+d]*invM; mu[1] = S[1*64+d]*invM;
  mu[2] = S[2*64+d]*invM; mu[3] = S[3*64+d]*invM;

  float A[4][4];
  A[0][0] = (float)(S[4*64+d]*invM  - mu[0]*mu[0] + EPSV);
  A[0][1] = A[1][0] = (float)(S[5*64+d]*invM  - mu[0]*mu[1]);
  A[0][2] = A[2][0] = (float)(S[6*64+d]*invM  - mu[0]*mu[2]);
  A[0][3] = A[3][0] = (float)(S[7*64+d]*invM  - mu[0]*mu[3]);
  A[1][1] = (float)(S[8*64+d]*invM  - mu[1]*mu[1] + EPSV);
  A[1][2] = A[2][1] = (float)(S[9*64+d]*invM  - mu[1]*mu[2]);
  A[1][3] = A[3][1] = (float)(S[10*64+d]*invM - mu[1]*mu[3]);
  A[2][2] = (float)(S[11*64+d]*invM - mu[2]*mu[2] + EPSV);
  A[2][3] = A[3][2] = (float)(S[12*64+d]*invM - mu[2]*mu[3]);
  A[3][3] = (float)(S[13*64+d]*invM - mu[3]*mu[3] + EPSV);

  float U[4][4] = {{1,0,0,0},{0,1,0,0},{0,0,1,0},{0,0,0,1}};

#pragma unroll 1
  for (int sweep = 0; sweep < 6; ++sweep) {
#pragma unroll
    for (int p = 0; p < 3; ++p) {
#pragma unroll
      for (int q = p + 1; q < 4; ++q) {
        float apq = A[p][q];
        if (fabsf(apq) > 1e-30f) {
          float theta = (A[q][q] - A[p][p]) / (2.0f * apq);
          float t = 1.0f / (fabsf(theta) + sqrtf(fmaf(theta, theta, 1.0f)));
          if (theta < 0.0f) t = -t;
          float c = rsqrtf(fmaf(t, t, 1.0f));
          float s = t * c;
#pragma unroll
          for (int r = 0; r < 4; ++r) {
            float arp = A[r][p], arq = A[r][q];
            A[r][p] = c*arp - s*arq;  A[r][q] = s*arp + c*arq;
          }
#pragma unroll
          for (int r = 0; r < 4; ++r) {
            float apr = A[p][r], aqr = A[q][r];
            A[p][r] = c*apr - s*aqr;  A[q][r] = s*apr + c*aqr;
          }
#pragma unroll
          for (int r = 0; r < 4; ++r) {
            float urp = U[r][p], urq = U[r][q];
            U[r][p] = c*urp - s*urq;  U[r][q] = s*urp + c*urq;
          }
        }
      }
    }
  }

  float wis[4];
#pragma unroll
  for (int b = 0; b < 4; ++b) {
    float w = A[b][b];
    if (w < 1e-12f) w = 1e-12f;
    wis[b] = rsqrtf(w);
  }

  float Wm[4][4];
#pragma unroll
  for (int a = 0; a < 4; ++a)
#pragma unroll
    for (int cc = 0; cc < 4; ++cc) {
      float acc = 0.0f;
#pragma unroll
      for (int b = 0; b < 4; ++b) acc += U[a][b] * wis[b] * U[cc][b];
      Wm[a][cc] = acc;
    }

  float G[4][4];
  G[0][0] = grr[d]; G[0][1] = G[1][0] = gri[d];
  G[0][2] = G[2][0] = grj[d]; G[0][3] = G[3][0] = grk[d];
  G[1][1] = gii[d]; G[1][2] = G[2][1] = gij[d];
  G[1][3] = G[3][1] = gik[d];
  G[2][2] = gjj[d]; G[2][3] = G[3][2] = gjk[d];
  G[3][3] = gkk[d];

  float M[4][4];
#pragma unroll
  for (int e = 0; e < 4; ++e)
#pragma unroll
    for (int cc = 0; cc < 4; ++cc) {
      float acc = 0.0f;
#pragma unroll
      for (int b = 0; b < 4; ++b) acc += G[e][b] * Wm[b][cc];
      M[e][cc] = acc;
      Mout[e*4 + cc] = acc;
    }

#pragma unroll
  for (int e = 0; e < 4; ++e) {
    float acc = beta[e*64 + d];
#pragma unroll
    for (int cc = 0; cc < 4; ++cc) acc -= M[e][cc] * (float)mu[cc];
    offout[e] = acc;
  }
}

// ---------------------------------------------------------------------------
// Kernel 3: solve (prologue, redundant per block, threads 0-63 -> LDS) +
// apply stream: contiguous 1KB/wave, LDS transpose, NT f32x4 stores.
// Lane l's output channels 4l..4l+3 == component e=l>>4, d-quad l&15.
// ---------------------------------------------------------------------------
__global__ __launch_bounds__(256) void hbn_apply(const float* __restrict__ x,
                                                 const double* __restrict__ S,
                                                 const float* __restrict__ beta,
                                                 const float* __restrict__ grr, const float* __restrict__ gri,
                                                 const float* __restrict__ grj, const float* __restrict__ grk,
                                                 const float* __restrict__ gii, const float* __restrict__ gij,
                                                 const float* __restrict__ gik, const float* __restrict__ gjj,
                                                 const float* __restrict__ gjk, const float* __restrict__ gkk,
                                                 float* __restrict__ out) {
  const int tid  = threadIdx.x;
  const int lane = tid & 63;
  const int wib  = tid >> 6;
  const int dq   = lane & 15;
  const int e    = lane >> 4;
  const int gw   = blockIdx.x * 4 + wib;
  const int nw   = ABLK * 4;                 // 8192 waves

  __shared__ float stage[4][256];
  __shared__ float Ms[64 * 16];              // [(e*4+c)*64 + d]
  __shared__ float offs[256];                // [e*64 + d]
  float* st = &stage[wib][0];

  if (tid < 64) {
    float Mo[16], oo[4];
    solve_one(S, beta, grr, gri, grj, grk, gii, gij, gik, gjj, gjk, gkk,
              tid, Mo, oo);
#pragma unroll
    for (int ec = 0; ec < 16; ++ec) Ms[ec * 64 + tid] = Mo[ec];
#pragma unroll
    for (int q = 0; q < 4; ++q) offs[q * 64 + tid] = oo[q];
  }
  __syncthreads();

  f32x4 me[4];
#pragma unroll
  for (int c = 0; c < 4; ++c)
    me[c] = *reinterpret_cast<const f32x4*>(Ms + (e*4 + c)*64 + dq*4);
  const f32x4 ob = *reinterpret_cast<const f32x4*>(offs + e*64 + dq*4);

  for (int p = gw; p < NPOS; p += nw) {
    const f32x4 v = *reinterpret_cast<const f32x4*>(x + (size_t)p * CCH + lane * 4);
    *reinterpret_cast<f32x4*>(st + lane * 4) = v;
    const f32x4 r4 = *reinterpret_cast<const f32x4*>(st + 0   + dq * 4);
    const f32x4 i4 = *reinterpret_cast<const f32x4*>(st + 64  + dq * 4);
    const f32x4 j4 = *reinterpret_cast<const f32x4*>(st + 128 + dq * 4);
    const f32x4 k4 = *reinterpret_cast<const f32x4*>(st + 192 + dq * 4);

    f32x4 y;
#pragma unroll
    for (int t = 0; t < 4; ++t)
      y[t] = fmaf(me[0][t], r4[t],
             fmaf(me[1][t], i4[t],
             fmaf(me[2][t], j4[t],
             fmaf(me[3][t], k4[t], ob[t]))));
#pragma unroll
    for (int t = 0; t < 4; ++t) y[t] = eluf(y[t]);
    __builtin_nontemporal_store(y, reinterpret_cast<f32x4*>(out + (size_t)p * CCH + lane * 4));
  }
}

extern "C" void kernel_launch(void* const* d_in, const int* in_sizes, int n_in,
                              void* d_out, int out_size, void* d_ws, size_t ws_size,
                              hipStream_t stream) {
  (void)in_sizes; (void)n_in; (void)out_size; (void)ws_size;
  const float* x    = (const float*)d_in[0];
  const float* beta = (const float*)d_in[1];
  const float* grr  = (const float*)d_in[2];
  const float* gri  = (const float*)d_in[3];
  const float* grj  = (const float*)d_in[4];
  const float* grk  = (const float*)d_in[5];
  const float* gii  = (const float*)d_in[6];
  const float* gij  = (const float*)d_in[7];
  const float* gik  = (const float*)d_in[8];
  const float* gjj  = (const float*)d_in[9];
  const float* gjk  = (const float*)d_in[10];
  const float* gkk  = (const float*)d_in[11];
  float* out = (float*)d_out;

  double* S      = (double*)d_ws;                   // 896 f64
  float*  partial= (float*)((char*)d_ws + 12288);   // RB*896 f32

  hbn_reduce<<<RB, 256, 0, stream>>>(x, partial);
  hbn_sum<<<224, 256, 0, stream>>>(partial, S);
  hbn_apply<<<ABLK, 256, 0, stream>>>(x, S, beta, grr, gri, grj, grk,
                                      gii, gij, gik, gjj, gjk, gkk, out);
}